// Round 11
// baseline (270.513 us; speedup 1.0000x reference)
//
#include <hip/hip_runtime.h>
#include <hip/hip_bf16.h>

// Problem: pooled = tanh(hs @ W^T + b); out0 = pooled[:,0]; out1 = span-means;
// out2 = zeros(N,S).  N=64, L=512, H=768, S=16. Inputs fp32, d_out fp32.
//
// R16: invert the blocking -- A read ONCE, W streamed from L2.
// R15 closed the model: 460 MB cache traffic at ~6 TB/s == the wall; the 8x
// A re-read (384 MB) dominates. This round:
//  - Block = 64 A-rows x ALL 768 cols (512 blocks). A-tile 64x768 bf16 =
//    96 KB lives whole in LDS, reg-staged in the prologue from fp32 HBM
//    (global->cvt->swizzled ds_write, R8-proven). A: read once, fp32,
//    no convert dispatch for A (saves 192 MB of convert traffic + a launch).
//  - W (bf16 via tiny 2.4 MB convert_w dispatch) streamed GLOBAL->REG per
//    K-iter, distance-1 prefetch; 1.18 MB -> L2-resident per XCD (75 MB/XCD
//    through L2, overlapped with MFMA). A-read-once WITHOUT R12's per-iter
//    staging drains: after one prologue barrier the K-loop free-runs (no
//    barriers, no vmcnt drains) -- the structure proven to sustain high
//    fetch rates (R9/R14).
//  - Fragment math/swizzle identical to R14/R15 (af/wf sources swapped).
//  - Epilogue: R12's pre-scaled global-atomic span merge + memset.
#define NPASS 64
#define LSEQ  512
#define HDIM  768
#define NSPAN 16
#define MTOT  (NPASS*LSEQ)                        // 32768
#define OFF_SENT (NPASS*HDIM)                     // 49152
#define W_ELEMS (HDIM*HDIM)                       // 589824

#define BM   64                    // A-rows per block
#define BK   32
#define NK   (HDIM/BK)             // 24
#define NBLK (MTOT/BM)             // 512 (2 rounds on 256 CUs)
#define THREADS 512
#define NMT  4                     // row frags per wave (all 64 rows)
#define NTN  6                     // col frags per wave (96 cols)
#define GPR  (HDIM/8)              // 96 granules per row

typedef __bf16 bf16x8 __attribute__((ext_vector_type(8)));
typedef __bf16 bf16x4 __attribute__((ext_vector_type(4)));
typedef float  f32x4  __attribute__((ext_vector_type(4)));

__device__ inline unsigned short f2bf(float f) {
  __hip_bfloat16 h = __float2bfloat16(f);   // RNE
  unsigned short u; __builtin_memcpy(&u, &h, 2); return u;
}

// tanh via v_exp_f32: ~7 VALU ops vs ~25 for libm tanhf. |err| < 1e-6 rel.
__device__ inline float fast_tanh(float x) {
  const float ax = fabsf(x);
  const float t  = __expf(-2.0f * ax);
  const float r  = (1.0f - t) * __builtin_amdgcn_rcpf(1.0f + t);
  return copysignf(r, x);
}

// 8x fp32 -> bf16x8 (RNE via fptrunc; compiler emits v_cvt_pk_bf16_f32 pairs).
__device__ inline bf16x8 cvt8(f32x4 lo, f32x4 hi) {
  union { bf16x4 h[2]; bf16x8 v; } u;
  u.h[0] = __builtin_convertvector(lo, bf16x4);
  u.h[1] = __builtin_convertvector(hi, bf16x4);
  return u.v;
}

// fp32 -> bf16 one-shot convert of W only (2.4 MB). R6-verified.
__global__ __launch_bounds__(256) void convert_w_kernel(
    const float* __restrict__ W, unsigned short* __restrict__ Wb)
{
  const int i = (blockIdx.x * 256 + threadIdx.x) * 8;
  const float4 a = *(const float4*)(W + i);
  const float4 b = *(const float4*)(W + i + 4);
  union { unsigned short us[8]; uint4 v; } o;
  o.us[0]=f2bf(a.x); o.us[1]=f2bf(a.y); o.us[2]=f2bf(a.z); o.us[3]=f2bf(a.w);
  o.us[4]=f2bf(b.x); o.us[5]=f2bf(b.y); o.us[6]=f2bf(b.z); o.us[7]=f2bf(b.w);
  *(uint4*)(Wb + i) = o.v;
}

__global__ __launch_bounds__(THREADS, 2) void fused_kernel(
    const float* __restrict__ A,            // (32768, 768) fp32
    const unsigned short* __restrict__ Wb,  // (768, 768) bf16
    const float* __restrict__ bias,         // (768,)
    const int*   __restrict__ spans,        // (64,16,2)
    float* __restrict__ out)
{
  __shared__ __align__(16) unsigned short Al[BM * HDIM];   // 98304 B bf16
  __shared__ float inv_s[NSPAN];
  __shared__ float bias_s[HDIM];                           // 3 KB
  __shared__ short sid_l[BM];
  // total ~102 KB -> 1 block/CU, 8 waves (2/SIMD, 256-reg budget)

  const int tid  = threadIdx.x;
  const int b    = blockIdx.x;        // no inter-block A sharing: plain map
  const int p    = b >> 3;            // passage
  const int l0   = (b & 7) << 6;      // first local seq row
  const int row0 = b * BM;            // global A row

  const int wave = tid >> 6;          // 0..7 -> cols [wave*96, wave*96+96)
  const int lane = tid & 63;
  const int quad = lane >> 4;
  const int lr   = lane & 15;

  // ---- Prologue: reg-stage A (fp32 HBM -> cvt -> bf16 LDS, swizzled). ----
  // Layout: Al[r][kg'] with kg' = kg ^ (r&7) over 16B granules (8 bf16);
  // row stride 1536 B. Same swizzle family as R8..R15 (reads proven free).
  {
    #pragma unroll
    for (int j = 0; j < (BM * GPR) / THREADS; ++j) {       // 12
      const int g  = j * THREADS + tid;
      const int r  = g / GPR;               // 0..63
      const int kg = g % GPR;               // 0..95
      const float* src = A + (size_t)(row0 + r) * HDIM + kg * 8;
      const f32x4 lo = *(const f32x4*)src;
      const f32x4 hi = *(const f32x4*)(src + 4);
      *(bf16x8*)(Al + (size_t)r * HDIM + ((kg ^ (r & 7)) * 8)) = cvt8(lo, hi);
    }
  }

  // Tables.
  if (tid < BM) {
    const int l = l0 + tid;
    short s = -1;
    #pragma unroll
    for (int i = 0; i < NSPAN; ++i) {
      const int st = spans[(p * NSPAN + i) * 2 + 0];
      const int en = spans[(p * NSPAN + i) * 2 + 1];
      if (l >= st && l < en) s = (short)i;
    }
    sid_l[tid] = s;
  }
  if (tid < NSPAN)
    inv_s[tid] = 1.0f / (float)(spans[(p * NSPAN + tid) * 2 + 1] -
                                spans[(p * NSPAN + tid) * 2 + 0]);
  for (int i = tid; i < HDIM; i += THREADS) bias_s[i] = bias[i];

  __syncthreads();   // the ONLY barrier before the epilogue

  // ---- Zero-barrier K-loop: A from LDS, W global->reg (L2-hot). ----
  // W frag (B-operand): lane holds Wb[n = wave*96+nt*16+lr][k*32+quad*8..+8]
  // == one bf16x8. Same per-lane layout as R14 (verified), sources swapped.
  const unsigned short* Wp =
      Wb + (size_t)(wave * 96 + lr) * HDIM + quad * 8;

  f32x4 acc[NMT][NTN];
  #pragma unroll
  for (int mt = 0; mt < NMT; ++mt)
    #pragma unroll
    for (int nt = 0; nt < NTN; ++nt)
      acc[mt][nt] = (f32x4){0.f, 0.f, 0.f, 0.f};

  bf16x8 w_cur[NTN], w_nxt[NTN];
  #pragma unroll
  for (int nt = 0; nt < NTN; ++nt)
    w_cur[nt] = *(const bf16x8*)(Wp + (size_t)nt * 16 * HDIM);

  #pragma unroll
  for (int k = 0; k < NK; ++k) {
    // A fragments from LDS (swizzled, conflict-free: 8 granule-slots x 2
    // lanes per bank-group, proven R8..R15).
    bf16x8 af[NMT];
    #pragma unroll
    for (int mt = 0; mt < NMT; ++mt) {
      const int r  = mt * 16 + lr;
      const int kg = (4 * k + quad) ^ (r & 7);
      af[mt] = *(const bf16x8*)(Al + (size_t)r * HDIM + kg * 8);
    }
    // Prefetch next W frags (distance 1; L2-hot ~200 cyc, covered by MFMA).
    if (k + 1 < NK) {
      #pragma unroll
      for (int nt = 0; nt < NTN; ++nt)
        w_nxt[nt] = *(const bf16x8*)(Wp + (size_t)nt * 16 * HDIM + (k + 1) * BK);
    }
    __builtin_amdgcn_s_setprio(1);
    #pragma unroll
    for (int mt = 0; mt < NMT; ++mt)
      #pragma unroll
      for (int nt = 0; nt < NTN; ++nt)
        acc[mt][nt] = __builtin_amdgcn_mfma_f32_16x16x32_bf16(
            af[mt], w_cur[nt], acc[mt][nt], 0, 0, 0);
    __builtin_amdgcn_s_setprio(0);
    #pragma unroll
    for (int nt = 0; nt < NTN; ++nt) w_cur[nt] = w_nxt[nt];
  }

  // ---- Epilogue (R12-proven): C/D col=lane&15, row=quad*4+reg. ----
  // Run-merged, pre-scaled global atomics into memset-zeroed out.
  #pragma unroll
  for (int nt = 0; nt < NTN; ++nt) {
    const int col = wave * 96 + nt * 16 + lr;      // 0..767
    const float bv = bias_s[col];
    float* sent_col = out + OFF_SENT + (size_t)(p * NSPAN) * HDIM + col;
    #pragma unroll
    for (int mt = 0; mt < NMT; ++mt) {
      const int rowbase = mt * 16 + quad * 4;      // local row 0..63
      int prev = -1; float run = 0.f;
      #pragma unroll
      for (int r = 0; r < 4; ++r) {
        const int row = rowbase + r;
        const float v = fast_tanh(acc[mt][nt][r] + bv);
        if (l0 == 0 && row == 0) out[(size_t)p * HDIM + col] = v;  // pooled[:,0]
        const int s = sid_l[row];
        if (s != prev) {
          if (prev >= 0) unsafeAtomicAdd(sent_col + (size_t)prev * HDIM, run * inv_s[prev]);
          prev = s; run = 0.f;
        }
        run += v;
      }
      if (prev >= 0) unsafeAtomicAdd(sent_col + (size_t)prev * HDIM, run * inv_s[prev]);
    }
  }
  // sentence_mask zeros: covered by the memset.
}

extern "C" void kernel_launch(void* const* d_in, const int* in_sizes, int n_in,
                              void* d_out, int out_size, void* d_ws, size_t ws_size,
                              hipStream_t stream) {
  const float* hs  = (const float*)d_in[0];  // (64,512,768) fp32
  const float* w   = (const float*)d_in[1];  // (768,768) fp32
  const float* bsc = (const float*)d_in[2];  // (768,) fp32
  // d_in[3] attention_mask unused
  const int* spans = (const int*)d_in[4];    // (64,16,2) int32
  float* out = (float*)d_out;

  unsigned short* Wb = (unsigned short*)d_ws;   // 1,179,648 B

  hipMemsetAsync(d_out, 0, (size_t)out_size * sizeof(float), stream);

  convert_w_kernel<<<dim3(W_ELEMS / 8 / 256), dim3(256), 0, stream>>>(w, Wb);

  fused_kernel<<<dim3(NBLK), dim3(THREADS), 0, stream>>>(
      hs, Wb, bsc, spans, out);
}

// Round 12
// 268.183 us; speedup vs baseline: 1.0087x; 1.0087x over previous
//
#include <hip/hip_runtime.h>
#include <hip/hip_bf16.h>

// Problem: pooled = tanh(hs @ W^T + b); out0 = pooled[:,0]; out1 = span-means;
// out2 = zeros(N,S).  N=64, L=512, H=768, S=16. Inputs fp32, d_out fp32.
//
// R17: R15's winning structure (W-in-LDS once, A streamed global->reg,
// free-run K-loop) with the per-XCD hot set pushed UNDER L2:
//  - persistent 256 blocks (1/CU); block = (xcd, N-tile, slot) loops over
//    4 HALF-PASSAGE chunks (256 rows). At step pi all blocks on an XCD
//    touch half-passages {4pi..4pi+3} = 2 passages x 768 KB bf16 = 1.5 MB
//    + W 1.2 MB = 2.7 MB < 4 MB L2  (R15: 4.2 MB -> L3-served re-reads at
//    ~6 TB/s == the 81 us wall; R14: 5.3 MB -> 87 us; trend confirmed).
//    The 8x A re-read (384 MB) becomes L2-local (~11 us aggregate).
//  - A-frag loads: R14-verified direct bf16x8 fragments, distance-2 parity
//    ring (static under full unroll; 2 waves/SIMD -> 256-reg budget, ~150
//    used, no R11-style spill).
//  - Spans may cross the half-passage boundary (sibling block) -> R12's
//    pre-scaled global unsafeAtomicAdd epilogue + memset (atomics proven
//    not a wall, R10).
#define NPASS 64
#define LSEQ  512
#define HDIM  768
#define NSPAN 16
#define MTOT  (NPASS*LSEQ)                        // 32768
#define OFF_SENT (NPASS*HDIM)                     // 49152
#define A_ELEMS (MTOT*HDIM)                       // 25165824
#define W_ELEMS (HDIM*HDIM)                       // 589824

#define BN   96
#define NTN  6                     // col frags per wave
#define BK   32
#define NK   (HDIM/BK)             // 24
#define NBLK 256                   // persistent: 1 block/CU
#define THREADS 512
#define NMT  2                     // row frags per wave (32 rows/wave)
#define CROWS 256                  // rows per chunk (half passage)

typedef __bf16 bf16x8 __attribute__((ext_vector_type(8)));
typedef __bf16 bf16x4 __attribute__((ext_vector_type(4)));
typedef float  f32x4  __attribute__((ext_vector_type(4)));

__device__ inline unsigned short f2bf(float f) {
  __hip_bfloat16 h = __float2bfloat16(f);   // RNE
  unsigned short u; __builtin_memcpy(&u, &h, 2); return u;
}

// tanh via v_exp_f32: ~7 VALU ops vs ~25 for libm tanhf. |err| < 1e-6 rel.
__device__ inline float fast_tanh(float x) {
  const float ax = fabsf(x);
  const float t  = __expf(-2.0f * ax);
  const float r  = (1.0f - t) * __builtin_amdgcn_rcpf(1.0f + t);
  return copysignf(r, x);
}

// fp32 -> bf16 one-shot convert of A then W. 8 elems/thread, 16B stores.
__global__ __launch_bounds__(256) void convert_kernel(
    const float* __restrict__ A, const float* __restrict__ W,
    unsigned short* __restrict__ Ab, unsigned short* __restrict__ Wb)
{
  const long long i = ((long long)blockIdx.x * 256 + threadIdx.x) * 8;
  const float* src; unsigned short* dst; long long off;
  if (i < A_ELEMS) { src = A; dst = Ab; off = i; }
  else             { src = W; dst = Wb; off = i - A_ELEMS; }
  const float4 a = *(const float4*)(src + off);
  const float4 b = *(const float4*)(src + off + 4);
  union { unsigned short us[8]; uint4 v; } o;
  o.us[0]=f2bf(a.x); o.us[1]=f2bf(a.y); o.us[2]=f2bf(a.z); o.us[3]=f2bf(a.w);
  o.us[4]=f2bf(b.x); o.us[5]=f2bf(b.y); o.us[6]=f2bf(b.z); o.us[7]=f2bf(b.w);
  *(uint4*)(dst + off) = o.v;
}

__global__ __launch_bounds__(THREADS, 2) void fused_kernel(
    const unsigned short* __restrict__ Ab,  // (32768, 768) bf16
    const unsigned short* __restrict__ Wb,  // (768, 768) bf16
    const float* __restrict__ bias,         // (768,)
    const int*   __restrict__ spans,        // (64,16,2)
    float* __restrict__ out)
{
  __shared__ __align__(16) unsigned short Wl[BN * HDIM];   // 147456 B bf16
  __shared__ float inv_s[NSPAN];
  __shared__ float bias_s[BN];
  __shared__ short sid_l[CROWS];                           // 512 B
  // total ~148.5 KB -> 1 block/CU, 8 waves (2/SIMD, 256-reg budget)

  const int tid  = threadIdx.x;
  const int b    = blockIdx.x;
  const int xcd  = b & 7;
  const int t    = b >> 3;                // 0..31 per XCD
  const int ntb  = t & 7;                 // N-tile 0..7
  const int slot = t >> 3;                // 0..3
  const int tile_n = ntb * BN;

  const int wave = tid >> 6;            // 0..7 -> rows [wave*32, wave*32+32)
  const int lane = tid & 63;
  const int quad = lane >> 4;
  const int lr   = lane & 15;

  // ---- W stage (ONCE): bf16 copy via global_load_lds, pre-swizzled src
  // (rule #21: linear dest + same-XOR read). R15-proven.
  {
    #pragma unroll
    for (int j = 0; j < (BN * (HDIM / 8)) / THREADS; ++j) {   // 18
      const int gi = j * THREADS + tid;
      const int wr = gi / (HDIM / 8);        // 0..95 (W row = output col)
      const int kg = gi % (HDIM / 8);        // 0..95 (16B granule in K)
      const unsigned short* src =
          Wb + (size_t)(tile_n + wr) * HDIM + ((kg ^ (wr & 7)) * 8);
      __builtin_amdgcn_global_load_lds(
          (const __attribute__((address_space(1))) void*)src,
          (__attribute__((address_space(3))) void*)(Wl + (size_t)gi * 8),
          16, 0, 0);
    }
  }
  if (tid < BN) bias_s[tid] = bias[tile_n + tid];

  // ---- 4 half-passage chunks; all blocks on an XCD stay in the same
  // 2-passage window at each step (approx lockstep: identical work). ----
  for (int pi = 0; pi < 4; ++pi) {
    const int h  = pi * 4 + slot;           // half-passage index 0..15 (XCD-local)
    const int p  = xcd + 8 * (h >> 1);      // passage
    const int l0 = (h & 1) * CROWS;         // 0 or 256

    // Per-chunk tables.
    if (tid < CROWS) {
      const int l = l0 + tid;
      short s = -1;
      #pragma unroll
      for (int i = 0; i < NSPAN; ++i) {
        const int st = spans[(p * NSPAN + i) * 2 + 0];
        const int en = spans[(p * NSPAN + i) * 2 + 1];
        if (l >= st && l < en) s = (short)i;
      }
      sid_l[tid] = s;
    }
    if (tid < NSPAN)
      inv_s[tid] = 1.0f / (float)(spans[(p * NSPAN + tid) * 2 + 1] -
                                  spans[(p * NSPAN + tid) * 2 + 0]);
    __syncthreads();   // tables published (+ W gload_lds drained at pi=0)

    // ---- Free-run K-loop (R14-verified fragments), distance-2 A ring. ----
    const unsigned short* Abp =
        Ab + ((size_t)p * LSEQ + l0 + wave * 32 + lr) * HDIM + quad * 8;

    f32x4 acc[NMT][NTN];
    #pragma unroll
    for (int mt = 0; mt < NMT; ++mt)
      #pragma unroll
      for (int nt = 0; nt < NTN; ++nt)
        acc[mt][nt] = (f32x4){0.f, 0.f, 0.f, 0.f};

    bf16x8 areg[2][NMT];                    // parity ring, static under unroll
    #pragma unroll
    for (int mt = 0; mt < NMT; ++mt) {
      areg[0][mt] = *(const bf16x8*)(Abp + (size_t)mt * 16 * HDIM);
      areg[1][mt] = *(const bf16x8*)(Abp + (size_t)mt * 16 * HDIM + BK);
    }

    #pragma unroll
    for (int k = 0; k < NK; ++k) {
      const int q = k & 1;                  // compile-time after full unroll
      bf16x8 wf[NTN];
      #pragma unroll
      for (int nt = 0; nt < NTN; ++nt) {
        const int wr = nt * 16 + lr;
        const int kg = (4 * k + quad) ^ (lr & 7);
        wf[nt] = *(const bf16x8*)(Wl + (size_t)wr * HDIM + kg * 8);
      }
      bf16x8 a_use[NMT];
      #pragma unroll
      for (int mt = 0; mt < NMT; ++mt) a_use[mt] = areg[q][mt];
      if (k + 2 < NK) {                     // refill freed slot, 2 ahead
        #pragma unroll
        for (int mt = 0; mt < NMT; ++mt)
          areg[q][mt] = *(const bf16x8*)(Abp + (size_t)mt * 16 * HDIM + (k + 2) * BK);
      }
      __builtin_amdgcn_s_setprio(1);
      #pragma unroll
      for (int mt = 0; mt < NMT; ++mt)
        #pragma unroll
        for (int nt = 0; nt < NTN; ++nt)
          acc[mt][nt] = __builtin_amdgcn_mfma_f32_16x16x32_bf16(
              a_use[mt], wf[nt], acc[mt][nt], 0, 0, 0);
      __builtin_amdgcn_s_setprio(0);
    }

    // ---- Epilogue: C/D col=lane&15, row=quad*4+reg (validated). ----
    // Pre-scaled global atomics (spans may cross chunk boundary).
    #pragma unroll
    for (int nt = 0; nt < NTN; ++nt) {
      const int col = tile_n + nt * 16 + lr;
      const float bv = bias_s[nt * 16 + lr];
      float* sent_col = out + OFF_SENT + (size_t)(p * NSPAN) * HDIM + col;
      #pragma unroll
      for (int mt = 0; mt < NMT; ++mt) {
        const int rowbase = wave * 32 + mt * 16 + quad * 4;  // chunk row 0..255
        int prev = -1; float run = 0.f;
        #pragma unroll
        for (int r = 0; r < 4; ++r) {
          const int row = rowbase + r;
          const float v = fast_tanh(acc[mt][nt][r] + bv);
          if (l0 == 0 && row == 0) out[(size_t)p * HDIM + col] = v; // pooled[:,0]
          const int s = sid_l[row];
          if (s != prev) {
            if (prev >= 0) unsafeAtomicAdd(sent_col + (size_t)prev * HDIM, run * inv_s[prev]);
            prev = s; run = 0.f;
          }
          run += v;
        }
        if (prev >= 0) unsafeAtomicAdd(sent_col + (size_t)prev * HDIM, run * inv_s[prev]);
      }
    }
    __syncthreads();   // epilogue's sid_l reads done before next chunk rewrites
  }
  // sentence_mask zeros: covered by the memset.
}

extern "C" void kernel_launch(void* const* d_in, const int* in_sizes, int n_in,
                              void* d_out, int out_size, void* d_ws, size_t ws_size,
                              hipStream_t stream) {
  const float* hs  = (const float*)d_in[0];  // (64,512,768) fp32
  const float* w   = (const float*)d_in[1];  // (768,768) fp32
  const float* bsc = (const float*)d_in[2];  // (768,) fp32
  // d_in[3] attention_mask unused
  const int* spans = (const int*)d_in[4];    // (64,16,2) int32
  float* out = (float*)d_out;

  unsigned short* Ab = (unsigned short*)d_ws;   // 50,331,648 B
  unsigned short* Wb = Ab + A_ELEMS;            // +1,179,648 B

  hipMemsetAsync(d_out, 0, (size_t)out_size * sizeof(float), stream);

  convert_kernel<<<dim3((A_ELEMS + W_ELEMS) / 8 / 256), dim3(256), 0, stream>>>(
      hs, w, Ab, Wb);

  fused_kernel<<<dim3(NBLK), dim3(THREADS), 0, stream>>>(
      Ab, Wb, bsc, spans, out);
}